// Round 3
// baseline (12526.785 us; speedup 1.0000x reference)
//
#include <hip/hip_runtime.h>
#include <hip/hip_bf16.h>

// StyleGAN2 generator forward, MI355X round-3 (dtype-adaptive + small ws).
// Handles BOTH harness conventions: all-float tensors stored as f32 OR as bf16.
// A detector kernel reads `const` and writes a flag (0=bf16, 1=f32) to ws;
// every d_in load / d_out store dispatches on it. Internal activations and
// modulated weights are always bf16; internal mapping state f32.
//
// Workspace layout (byte offsets):
//   0        : int flag (16 B slot)
//   16       : xA   4096 f32
//   16400    : xB   4096 f32
//   32784    : s_all 4608 f32
//   51216    : wmod 3,465,472 bf16 (6,930,944 B)
//   6982160  : P    16,777,216 B bf16 (per-batch big activations)
//   23759376 : Q     4,194,304 B bf16 (per-batch small activations)
//   total 27,953,680 B (~26.7 MiB)

typedef __hip_bfloat16 bf16;

__device__ __forceinline__ float b2f(bf16 v){ return __bfloat162float(v); }
__device__ __forceinline__ bf16  f2b(float v){ return __float2bfloat16(v); }
// dtype-adaptive load/store for harness buffers
__device__ __forceinline__ float ldf(const void* p, size_t i, int isf32){
  return isf32 ? ((const float*)p)[i] : b2f(((const bf16*)p)[i]);
}
__device__ __forceinline__ void stf(void* p, size_t i, int isf32, float v){
  if (isf32) ((float*)p)[i] = v; else ((bf16*)p)[i] = f2b(v);
}

// ---------------- dtype detector ----------------
// bf16 gaussian data: ~100% of u16 words have exponent field in [96,150].
// f32 gaussian data read as u16: low half-words are ~uniform -> ~60% overall.
__global__ __launch_bounds__(256) void detect_dtype(const unsigned short* __restrict__ cst,
    int* __restrict__ flag){
  __shared__ int cnt[256];
  int t = threadIdx.x, c = 0;
  for (int i=t; i<4096; i+=256){
    unsigned short w = cst[i];
    int mag = w & 0x7FFF;
    int e = mag >> 7;
    if (mag == 0 || (e >= 96 && e <= 150)) c++;
  }
  cnt[t] = c; __syncthreads();
  for (int s=128; s>0; s>>=1){ if (t<s) cnt[t] += cnt[t+s]; __syncthreads(); }
  if (t == 0) *flag = (cnt[0] >= 3500) ? 0 : 1;
}

// ---------------- mapping network ----------------
__global__ __launch_bounds__(256) void map_init(const void* __restrict__ z,
    const int* __restrict__ labels, const void* __restrict__ emb,
    float* __restrict__ x0, const int* __restrict__ dflag){
  int isf32 = *dflag;
  int i = blockIdx.x*256 + threadIdx.x;          // 4096 total
  int b = i >> 9, k = i & 511;
  x0[i] = ldf(z, i, isf32) + ldf(emb, (size_t)labels[b]*512 + k, isf32);
}

// One dense layer + batchnorm(batch=8, biased var) + lrelu.
// grid 512 (one block per output feature j), block 64 (one wave).
__global__ __launch_bounds__(64) void map_layer(const float* __restrict__ xin,
    float* __restrict__ xout, const void* __restrict__ W, size_t wOff,
    const void* __restrict__ bl, const void* __restrict__ gl,
    const void* __restrict__ betal, size_t vOff, const int* __restrict__ dflag){
  int isf32 = *dflag;
  int j = blockIdx.x;
  int l = threadIdx.x;
  int b = l >> 3, sp = l & 7;
  float part = 0.f;
  int k0 = sp*64;
  size_t wrow = wOff + (size_t)j*512 + k0;
  for (int k=0; k<64; k++)
    part += xin[b*512 + k0 + k] * ldf(W, wrow + k, isf32);
  part += __shfl_xor(part, 1);
  part += __shfl_xor(part, 2);
  part += __shfl_xor(part, 4);
  float y = part + ldf(bl, vOff + j, isf32);
  float ys[8];
  float mu = 0.f;
  #pragma unroll
  for (int bb=0; bb<8; bb++){ ys[bb] = __shfl(y, bb*8); mu += ys[bb]; }
  mu *= 0.125f;
  float var = 0.f;
  #pragma unroll
  for (int bb=0; bb<8; bb++){ float d = ys[bb]-mu; var += d*d; }
  var *= 0.125f;
  float xn = (y-mu)*rsqrtf(var+1e-5f)*ldf(gl, vOff + j, isf32) + ldf(betal, vOff + j, isf32);
  xn = (xn >= 0.f) ? xn : 0.2f*xn;
  if (sp == 0) xout[b*512 + j] = xn;
}

// ---------------- styles: s[b][ci] = w[b,:]·m[ci,:] for all 7 convs ----------------
__global__ __launch_bounds__(64) void styles_kernel(const float* __restrict__ w,
    float* __restrict__ s_all,
    const void* m0, const void* m1, const void* m2, const void* m3,
    const void* m4, const void* m5, const void* m6, const int* __restrict__ dflag){
  int isf32 = *dflag;
  int id = blockIdx.x;                            // 4608
  const int offs[8] = {0,1024,2048,3072,3584,4096,4352,4608};
  const int cins[7] = {128,128,128,64,64,32,32};
  const void* ms[7] = {m0,m1,m2,m3,m4,m5,m6};
  int c = 0;
  while (id >= offs[c+1]) c++;
  int r = id - offs[c];
  int Cin = cins[c];
  int b = r / Cin, ci = r % Cin;
  int l = threadIdx.x;
  float acc = 0.f;
  for (int k=l; k<512; k+=64) acc += w[b*512 + k] * ldf(ms[c], (size_t)ci*512 + k, isf32);
  #pragma unroll
  for (int m=1; m<64; m<<=1) acc += __shfl_xor(acc, m);
  if (l == 0) s_all[id] = acc;
}

// ---------------- modulate + demodulate weights (store bf16) ----------------
__global__ __launch_bounds__(64) void modw_kernel(const float* __restrict__ s_all,
    bf16* __restrict__ wmod,
    const void* w0, const void* w1, const void* w2, const void* w3,
    const void* w4, const void* w5, const void* w6, const int* __restrict__ dflag){
  int isf32 = *dflag;
  int bid = blockIdx.x;
  int base, Cout, Cin, soff, wmoff, demod = 1;
  const void* wp;
  if      (bid < 1024){ base=0;    Cout=128; Cin=128; soff=0;    wmoff=0;       wp=w0; }
  else if (bid < 2048){ base=1024; Cout=128; Cin=128; soff=1024; wmoff=1179648; wp=w1; }
  else if (bid < 2560){ base=2048; Cout=64;  Cin=128; soff=2048; wmoff=2359296; wp=w2; }
  else if (bid < 3072){ base=2560; Cout=64;  Cin=64;  soff=3072; wmoff=2949120; wp=w3; }
  else if (bid < 3328){ base=3072; Cout=32;  Cin=64;  soff=3584; wmoff=3244032; wp=w4; }
  else if (bid < 3584){ base=3328; Cout=32;  Cin=32;  soff=4096; wmoff=3391488; wp=w5; }
  else                { base=3584; Cout=1;   Cin=32;  soff=4352; wmoff=3465216; wp=w6; demod=0; }
  int kk = demod ? 9 : 1;
  int L  = Cin * kk;
  int bc = bid - base;
  int b  = bc / Cout, co = bc % Cout;
  float scale = 1.0f / sqrtf((float)L);
  int l = threadIdx.x;
  float part = 0.f;
  for (int e=l; e<L; e+=64){
    int ci = e / kk;
    float v = scale * ldf(wp, (size_t)co*L + e, isf32) * s_all[soff + b*Cin + ci];
    part += v*v;
  }
  #pragma unroll
  for (int m=1; m<64; m<<=1) part += __shfl_xor(part, m);
  float d = demod ? rsqrtf(part + 1e-8f) : 1.0f;
  for (int e=l; e<L; e+=64){
    int ci = e / kk;
    float v = scale * ldf(wp, (size_t)co*L + e, isf32) * s_all[soff + b*Cin + ci];
    wmod[wmoff + ((size_t)(b*Cout + co))*L + e] = f2b(v * d);
  }
}

// ---------------- 3x3 conv, stride 1, pad 1, fused noise+lrelu ----------------
// grid: (tiles(32x32), Cout/16, 1); block 256 = 16x16 threads, 2x2 micro-tile.
// xext=1: X is a harness buffer (dtype per flag, shared across batches).
__global__ __launch_bounds__(256) void conv3x3_s1(const void* __restrict__ X,
    int xext, int Cin, int H,
    const bf16* __restrict__ Wm, const void* __restrict__ noise,
    const void* __restrict__ nw, bf16* __restrict__ Y,
    int Cout, int b0, const int* __restrict__ dflag){
  int isf32 = *dflag;
  int xf = xext ? isf32 : 0;
  const int W = H;
  const int tilesX = H >> 5;
  int tile = blockIdx.x;
  int tx0 = (tile % tilesX) * 32;
  int ty0 = (tile / tilesX) * 32;
  int coB = blockIdx.y * 16;
  int gb  = b0;
  __shared__ float tin[8][34][36];
  __shared__ float wl[8][16][12];
  int t = threadIdx.x;
  float acc[16][2][2];
  #pragma unroll
  for (int co=0; co<16; co++){ acc[co][0][0]=0; acc[co][0][1]=0; acc[co][1][0]=0; acc[co][1][1]=0; }
  int oy = (t >> 4) << 1, ox = (t & 15) << 1;
  int nchunks = Cin >> 3;
  #pragma unroll 1
  for (int ch=0; ch<nchunks; ch++){
    int c0 = ch*8;
    for (int i=t; i<8*34*34; i+=256){
      int ci = i / 1156, rem = i % 1156, y = rem / 34, x = rem % 34;
      int gy = ty0 - 1 + y, gx = tx0 - 1 + x;
      float v = 0.f;
      if (gy>=0 && gy<H && gx>=0 && gx<W)
        v = ldf(X, (size_t)(c0+ci)*H*W + (size_t)gy*W + gx, xf);
      tin[ci][y][x] = v;
    }
    for (int i=t; i<8*16*9; i+=256){
      int ci = i / 144, r = i % 144, co = r/9, k = r%9;
      wl[ci][co][k] = b2f(Wm[(((size_t)gb*Cout + coB+co)*Cin + c0+ci)*9 + k]);
    }
    __syncthreads();
    #pragma unroll 1
    for (int ci=0; ci<8; ci++){
      float in[4][4];
      #pragma unroll
      for (int r=0; r<4; r++){
        const float* row = &tin[ci][oy+r][ox];
        in[r][0]=row[0]; in[r][1]=row[1]; in[r][2]=row[2]; in[r][3]=row[3];
      }
      #pragma unroll
      for (int co=0; co<16; co++){
        const float4* wv = reinterpret_cast<const float4*>(&wl[ci][co][0]);
        float4 wa = wv[0], wb = wv[1];
        float w8 = wl[ci][co][8];
        #pragma unroll
        for (int r2=0; r2<2; r2++)
          #pragma unroll
          for (int c2=0; c2<2; c2++){
            acc[co][r2][c2] += wa.x*in[r2  ][c2] + wa.y*in[r2  ][c2+1] + wa.z*in[r2  ][c2+2]
                             + wa.w*in[r2+1][c2] + wb.x*in[r2+1][c2+1] + wb.y*in[r2+1][c2+2]
                             + wb.z*in[r2+2][c2] + wb.w*in[r2+2][c2+1] + w8  *in[r2+2][c2+2];
          }
      }
    }
    __syncthreads();
  }
  float nwv[16];
  #pragma unroll
  for (int co=0; co<16; co++) nwv[co] = ldf(nw, coB+co, isf32);
  #pragma unroll
  for (int r2=0; r2<2; r2++)
    #pragma unroll
    for (int c2=0; c2<2; c2++){
      int gy = ty0 + oy + r2, gx = tx0 + ox + c2;
      float n = ldf(noise, ((size_t)gb*H + gy)*W + gx, isf32);
      #pragma unroll
      for (int co=0; co<16; co++){
        float v = acc[co][r2][c2] + nwv[co] * n;
        v = (v >= 0.f) ? v : 0.2f*v;
        Y[((size_t)(coB+co)*H + gy)*W + gx] = f2b(v);
      }
    }
}

// ---------------- 3x3 conv, stride 2, pad 1, fused noise+lrelu ----------------
__global__ __launch_bounds__(256) void conv3x3_s2(const bf16* __restrict__ X,
    int Cin, int Hin,
    const bf16* __restrict__ Wm, const void* __restrict__ noise,
    const void* __restrict__ nw, bf16* __restrict__ Y,
    int Cout, int b0, const int* __restrict__ dflag){
  int isf32 = *dflag;
  const int Win = Hin;
  const int Ho = Hin >> 1, Wo = Ho;
  const int tilesX = Ho >> 4;
  int tile = blockIdx.x;
  int tx0 = (tile % tilesX) * 16;   // output coords
  int ty0 = (tile / tilesX) * 16;
  int coB = blockIdx.y * 16;
  int gb  = b0;
  __shared__ float tin[8][33][34];
  __shared__ float wl[8][16][12];
  int t = threadIdx.x;
  float acc[16];
  #pragma unroll
  for (int co=0; co<16; co++) acc[co] = 0.f;
  int oy = t >> 4, ox = t & 15;
  int nchunks = Cin >> 3;
  #pragma unroll 1
  for (int ch=0; ch<nchunks; ch++){
    int c0 = ch*8;
    for (int i=t; i<8*33*33; i+=256){
      int ci = i / 1089, rem = i % 1089, y = rem / 33, x = rem % 33;
      int gy = 2*ty0 - 1 + y, gx = 2*tx0 - 1 + x;
      float v = 0.f;
      if (gy>=0 && gy<Hin && gx>=0 && gx<Win)
        v = b2f(X[(size_t)(c0+ci)*Hin*Win + (size_t)gy*Win + gx]);
      tin[ci][y][x] = v;
    }
    for (int i=t; i<8*16*9; i+=256){
      int ci = i / 144, r = i % 144, co = r/9, k = r%9;
      wl[ci][co][k] = b2f(Wm[(((size_t)gb*Cout + coB+co)*Cin + c0+ci)*9 + k]);
    }
    __syncthreads();
    #pragma unroll 1
    for (int ci=0; ci<8; ci++){
      float in9[3][3];
      #pragma unroll
      for (int r=0; r<3; r++){
        const float* row = &tin[ci][2*oy + r][2*ox];
        in9[r][0]=row[0]; in9[r][1]=row[1]; in9[r][2]=row[2];
      }
      #pragma unroll
      for (int co=0; co<16; co++){
        const float4* wv = reinterpret_cast<const float4*>(&wl[ci][co][0]);
        float4 wa = wv[0], wb = wv[1];
        float w8 = wl[ci][co][8];
        acc[co] += wa.x*in9[0][0] + wa.y*in9[0][1] + wa.z*in9[0][2]
                 + wa.w*in9[1][0] + wb.x*in9[1][1] + wb.y*in9[1][2]
                 + wb.z*in9[2][0] + wb.w*in9[2][1] + w8  *in9[2][2];
      }
    }
    __syncthreads();
  }
  int gy = ty0 + oy, gx = tx0 + ox;
  float n = ldf(noise, ((size_t)gb*Ho + gy)*Wo + gx, isf32);
  #pragma unroll
  for (int co=0; co<16; co++){
    float v = acc[co] + ldf(nw, coB+co, isf32) * n;
    v = (v >= 0.f) ? v : 0.2f*v;
    Y[((size_t)(coB+co)*Ho + gy)*Wo + gx] = f2b(v);
  }
}

// ---------------- bilinear resize (32x32 -> 256x240) + 1x1 to-gray, one batch ----------------
__global__ __launch_bounds__(256) void resize_rgb(const bf16* __restrict__ X,
    const bf16* __restrict__ wr, void* __restrict__ out, int b0,
    const int* __restrict__ dflag){
  int isf32 = *dflag;
  int i = blockIdx.x*256 + threadIdx.x;           // 61440 per batch, grid 240
  int x = i % 240;
  int y = i / 240;
  float sy = (y + 0.5f)*0.125f - 0.5f;
  float sx = (x + 0.5f)*(32.0f/240.0f) - 0.5f;
  float y0f = floorf(sy), x0f = floorf(sx);
  float fy = sy - y0f, fx = sx - x0f;
  int y0 = (int)y0f, x0 = (int)x0f;
  int y1 = min(y0+1, 31), x1 = min(x0+1, 31);
  y0 = max(y0, 0); x0 = max(x0, 0);
  float acc = 0.f;
  for (int ci=0; ci<32; ci++){
    const bf16* p = X + (size_t)ci*1024;
    float v00 = b2f(p[y0*32 + x0]), v01 = b2f(p[y0*32 + x1]);
    float v10 = b2f(p[y1*32 + x0]), v11 = b2f(p[y1*32 + x1]);
    float v = (1.f-fy)*((1.f-fx)*v00 + fx*v01) + fy*((1.f-fx)*v10 + fx*v11);
    acc += b2f(wr[b0*32 + ci]) * v;
  }
  stf(out, (size_t)b0*61440 + i, isf32, acc);
}

extern "C" void kernel_launch(void* const* d_in, const int* in_sizes, int n_in,
                              void* d_out, int out_size, void* d_ws, size_t ws_size,
                              hipStream_t stream){
  const void* z        = d_in[0];
  const int*  labels   = (const int*)d_in[1];
  const void* emb      = d_in[2];
  const void* map_W    = d_in[3];
  const void* map_b    = d_in[4];
  const void* map_g    = d_in[5];
  const void* map_beta = d_in[6];
  const void* cst      = d_in[7];
  const void* cw0 = d_in[8];   const void* cm0 = d_in[9];
  const void* cw1 = d_in[10];  const void* cm1 = d_in[11];
  const void* n1w = d_in[12];  const void* n2w = d_in[13];
  const void* cw2 = d_in[14];  const void* cm2 = d_in[15];
  const void* cw3 = d_in[16];  const void* cm3 = d_in[17];
  const void* n3w = d_in[18];  const void* n4w = d_in[19];
  const void* cw4 = d_in[20];  const void* cm4 = d_in[21];
  const void* cw5 = d_in[22];  const void* cm5 = d_in[23];
  const void* n5w = d_in[24];  const void* n6w = d_in[25];
  const void* cw6 = d_in[26];  const void* cm6 = d_in[27];
  const void* n1a = d_in[28];  const void* n1b = d_in[29];
  const void* n2a = d_in[30];  const void* n2b = d_in[31];
  const void* n3a = d_in[32];  const void* n3b = d_in[33];

  int*   flag  = (int*)d_ws;
  float* xA    = (float*)((char*)d_ws + 16);
  float* xB    = (float*)((char*)d_ws + 16400);
  float* s_all = (float*)((char*)d_ws + 32784);
  bf16*  wmod  = (bf16*)((char*)d_ws + 51216);
  bf16*  P     = (bf16*)((char*)d_ws + 6982160);   // 16,777,216 B
  bf16*  Q     = (bf16*)((char*)d_ws + 23759376);  //  4,194,304 B
  // total 27,953,680 B

  detect_dtype<<<1,256,0,stream>>>((const unsigned short*)cst, flag);
  map_init<<<16,256,0,stream>>>(z, labels, emb, xA, flag);
  float* cur = xA; float* nxt = xB;
  for (int l=0; l<8; l++){
    map_layer<<<512,64,0,stream>>>(cur, nxt, map_W, (size_t)l*512*512,
                                   map_b, map_g, map_beta, (size_t)l*512, flag);
    float* tmp = cur; cur = nxt; nxt = tmp;
  }
  // cur == xA holds final w
  styles_kernel<<<4608,64,0,stream>>>(cur, s_all, cm0, cm1, cm2, cm3, cm4, cm5, cm6, flag);
  modw_kernel<<<3592,64,0,stream>>>(s_all, wmod, cw0, cw1, cw2, cw3, cw4, cw5, cw6, flag);

  bf16* wm0 = wmod;
  bf16* wm1 = wmod + 1179648;
  bf16* wm2 = wmod + 2359296;
  bf16* wm3 = wmod + 2949120;
  bf16* wm4 = wmod + 3244032;
  bf16* wm5 = wmod + 3391488;
  bf16* wm6 = wmod + 3465216;

  for (int b=0; b<8; b++){
    // b1: cst -> P (128x256x256) -> Q (128x128x128)
    conv3x3_s1<<<dim3(64,8,1),256,0,stream>>>(cst, 1, 128, 256, wm0, n1a, n1w, P, 128, b, flag);
    conv3x3_s2<<<dim3(64,8,1),256,0,stream>>>(P, 128, 256, wm1, n1b, n2w, Q, 128, b, flag);
    // b2: Q -> P (64x128x128) -> Q (64x64x64)
    conv3x3_s1<<<dim3(16,4,1),256,0,stream>>>(Q, 0, 128, 128, wm2, n2a, n3w, P, 64, b, flag);
    conv3x3_s2<<<dim3(16,4,1),256,0,stream>>>(P, 64, 128, wm3, n2b, n4w, Q, 64, b, flag);
    // b3: Q -> P (32x64x64) -> Q (32x32x32)
    conv3x3_s1<<<dim3(4,2,1),256,0,stream>>>(Q, 0, 64, 64, wm4, n3a, n5w, P, 32, b, flag);
    conv3x3_s2<<<dim3(4,2,1),256,0,stream>>>(P, 32, 64, wm5, n3b, n6w, Q, 32, b, flag);
    // resize + to-gray 1x1 (no demod) -> d_out
    resize_rgb<<<240,256,0,stream>>>(Q, wm6, d_out, b, flag);
  }
}

// Round 4
// 6043.128 us; speedup vs baseline: 2.0729x; 2.0729x over previous
//
#include <hip/hip_runtime.h>
#include <hip/hip_bf16.h>

// StyleGAN2 generator forward, MI355X round-4: batched convs (blockIdx.z) with
// host-side ws_size-gated memory layout. Inputs detected f32 in round 3 (via
// FETCH_SIZE); detector kept for safety. Conv math identical to round 3.
//
// Layouts (byte offsets; misc block shared):
//   0      : int flag (256 B slot)
//   256    : xA 4096 f32
//   16640  : xB 4096 f32
//   33024  : s_all 4608 f32
//   51456  : wmod 3,465,472 bf16 (6,930,944 B) -> end 6,982,400; arenas @ 6,983,680
// Path A (ws >= 174,755,840): arenaA 134,217,728 (a1 / a2 / a3),
//                             arenaB  33,554,432 (a1b / a2b / a3b). Full z=8.
// Path B (ws >=  61,509,632): arenaA 16,777,216 (a1 per-batch / a2 / a3),
//                             arenaB 33,554,432 (a1b full / a3 scratch),
//                             arenaC  4,194,304 (a2b / a3b). b1 per-batch, rest z=8.
// Path C (fallback, 27,955,200): round-3 per-batch ping-pong.

typedef __hip_bfloat16 bf16;

__device__ __forceinline__ float b2f(bf16 v){ return __bfloat162float(v); }
__device__ __forceinline__ bf16  f2b(float v){ return __float2bfloat16(v); }
__device__ __forceinline__ float ldf(const void* p, size_t i, int isf32){
  return isf32 ? ((const float*)p)[i] : b2f(((const bf16*)p)[i]);
}
__device__ __forceinline__ void stf(void* p, size_t i, int isf32, float v){
  if (isf32) ((float*)p)[i] = v; else ((bf16*)p)[i] = f2b(v);
}

// ---------------- dtype detector ----------------
__global__ __launch_bounds__(256) void detect_dtype(const unsigned short* __restrict__ cst,
    int* __restrict__ flag){
  __shared__ int cnt[256];
  int t = threadIdx.x, c = 0;
  for (int i=t; i<4096; i+=256){
    unsigned short w = cst[i];
    int mag = w & 0x7FFF;
    int e = mag >> 7;
    if (mag == 0 || (e >= 96 && e <= 150)) c++;
  }
  cnt[t] = c; __syncthreads();
  for (int s=128; s>0; s>>=1){ if (t<s) cnt[t] += cnt[t+s]; __syncthreads(); }
  if (t == 0) *flag = (cnt[0] >= 3500) ? 0 : 1;
}

// ---------------- mapping network ----------------
__global__ __launch_bounds__(256) void map_init(const void* __restrict__ z,
    const int* __restrict__ labels, const void* __restrict__ emb,
    float* __restrict__ x0, const int* __restrict__ dflag){
  int isf32 = *dflag;
  int i = blockIdx.x*256 + threadIdx.x;          // 4096 total
  int b = i >> 9, k = i & 511;
  x0[i] = ldf(z, i, isf32) + ldf(emb, (size_t)labels[b]*512 + k, isf32);
}

__global__ __launch_bounds__(64) void map_layer(const float* __restrict__ xin,
    float* __restrict__ xout, const void* __restrict__ W, size_t wOff,
    const void* __restrict__ bl, const void* __restrict__ gl,
    const void* __restrict__ betal, size_t vOff, const int* __restrict__ dflag){
  int isf32 = *dflag;
  int j = blockIdx.x;
  int l = threadIdx.x;
  int b = l >> 3, sp = l & 7;
  float part = 0.f;
  int k0 = sp*64;
  size_t wrow = wOff + (size_t)j*512 + k0;
  for (int k=0; k<64; k++)
    part += xin[b*512 + k0 + k] * ldf(W, wrow + k, isf32);
  part += __shfl_xor(part, 1);
  part += __shfl_xor(part, 2);
  part += __shfl_xor(part, 4);
  float y = part + ldf(bl, vOff + j, isf32);
  float ys[8];
  float mu = 0.f;
  #pragma unroll
  for (int bb=0; bb<8; bb++){ ys[bb] = __shfl(y, bb*8); mu += ys[bb]; }
  mu *= 0.125f;
  float var = 0.f;
  #pragma unroll
  for (int bb=0; bb<8; bb++){ float d = ys[bb]-mu; var += d*d; }
  var *= 0.125f;
  float xn = (y-mu)*rsqrtf(var+1e-5f)*ldf(gl, vOff + j, isf32) + ldf(betal, vOff + j, isf32);
  xn = (xn >= 0.f) ? xn : 0.2f*xn;
  if (sp == 0) xout[b*512 + j] = xn;
}

// ---------------- styles ----------------
__global__ __launch_bounds__(64) void styles_kernel(const float* __restrict__ w,
    float* __restrict__ s_all,
    const void* m0, const void* m1, const void* m2, const void* m3,
    const void* m4, const void* m5, const void* m6, const int* __restrict__ dflag){
  int isf32 = *dflag;
  int id = blockIdx.x;                            // 4608
  const int offs[8] = {0,1024,2048,3072,3584,4096,4352,4608};
  const int cins[7] = {128,128,128,64,64,32,32};
  const void* ms[7] = {m0,m1,m2,m3,m4,m5,m6};
  int c = 0;
  while (id >= offs[c+1]) c++;
  int r = id - offs[c];
  int Cin = cins[c];
  int b = r / Cin, ci = r % Cin;
  int l = threadIdx.x;
  float acc = 0.f;
  for (int k=l; k<512; k+=64) acc += w[b*512 + k] * ldf(ms[c], (size_t)ci*512 + k, isf32);
  #pragma unroll
  for (int m=1; m<64; m<<=1) acc += __shfl_xor(acc, m);
  if (l == 0) s_all[id] = acc;
}

// ---------------- modulate + demodulate weights (store bf16) ----------------
__global__ __launch_bounds__(64) void modw_kernel(const float* __restrict__ s_all,
    bf16* __restrict__ wmod,
    const void* w0, const void* w1, const void* w2, const void* w3,
    const void* w4, const void* w5, const void* w6, const int* __restrict__ dflag){
  int isf32 = *dflag;
  int bid = blockIdx.x;
  int base, Cout, Cin, soff, wmoff, demod = 1;
  const void* wp;
  if      (bid < 1024){ base=0;    Cout=128; Cin=128; soff=0;    wmoff=0;       wp=w0; }
  else if (bid < 2048){ base=1024; Cout=128; Cin=128; soff=1024; wmoff=1179648; wp=w1; }
  else if (bid < 2560){ base=2048; Cout=64;  Cin=128; soff=2048; wmoff=2359296; wp=w2; }
  else if (bid < 3072){ base=2560; Cout=64;  Cin=64;  soff=3072; wmoff=2949120; wp=w3; }
  else if (bid < 3328){ base=3072; Cout=32;  Cin=64;  soff=3584; wmoff=3244032; wp=w4; }
  else if (bid < 3584){ base=3328; Cout=32;  Cin=32;  soff=4096; wmoff=3391488; wp=w5; }
  else                { base=3584; Cout=1;   Cin=32;  soff=4352; wmoff=3465216; wp=w6; demod=0; }
  int kk = demod ? 9 : 1;
  int L  = Cin * kk;
  int bc = bid - base;
  int b  = bc / Cout, co = bc % Cout;
  float scale = 1.0f / sqrtf((float)L);
  int l = threadIdx.x;
  float part = 0.f;
  for (int e=l; e<L; e+=64){
    int ci = e / kk;
    float v = scale * ldf(wp, (size_t)co*L + e, isf32) * s_all[soff + b*Cin + ci];
    part += v*v;
  }
  #pragma unroll
  for (int m=1; m<64; m<<=1) part += __shfl_xor(part, m);
  float d = demod ? rsqrtf(part + 1e-8f) : 1.0f;
  for (int e=l; e<L; e+=64){
    int ci = e / kk;
    float v = scale * ldf(wp, (size_t)co*L + e, isf32) * s_all[soff + b*Cin + ci];
    wmod[wmoff + ((size_t)(b*Cout + co))*L + e] = f2b(v * d);
  }
}

// ---------------- 3x3 conv, stride 1, pad 1, fused noise+lrelu ----------------
// grid: (tiles(32x32), Cout/16, nb). gb = b0+z indexes weights/noise;
// X/Y offset by z*{xbs,ybs} elements. xext: X is a harness buffer (flag dtype).
__global__ __launch_bounds__(256) void conv3x3_s1(const void* __restrict__ X,
    int xext, long long xbs, int Cin, int H,
    const bf16* __restrict__ Wm, const void* __restrict__ noise,
    const void* __restrict__ nw, bf16* __restrict__ Y, long long ybs,
    int Cout, int b0, const int* __restrict__ dflag){
  int isf32 = *dflag;
  int xf = xext ? isf32 : 0;
  const int W = H;
  const int tilesX = H >> 5;
  int tile = blockIdx.x;
  int tx0 = (tile % tilesX) * 32;
  int ty0 = (tile / tilesX) * 32;
  int coB = blockIdx.y * 16;
  int zz  = blockIdx.z;
  int gb  = b0 + zz;
  __shared__ float tin[8][34][36];
  __shared__ float wl[8][16][12];
  int t = threadIdx.x;
  const char* Xb = (const char*)X + (size_t)zz * xbs * (xf ? 4 : 2);
  bf16*       Yb = Y + (size_t)zz * ybs;
  float acc[16][2][2];
  #pragma unroll
  for (int co=0; co<16; co++){ acc[co][0][0]=0; acc[co][0][1]=0; acc[co][1][0]=0; acc[co][1][1]=0; }
  int oy = (t >> 4) << 1, ox = (t & 15) << 1;
  int nchunks = Cin >> 3;
  #pragma unroll 1
  for (int ch=0; ch<nchunks; ch++){
    int c0 = ch*8;
    for (int i=t; i<8*34*34; i+=256){
      int ci = i / 1156, rem = i % 1156, y = rem / 34, x = rem % 34;
      int gy = ty0 - 1 + y, gx = tx0 - 1 + x;
      float v = 0.f;
      if (gy>=0 && gy<H && gx>=0 && gx<W)
        v = ldf(Xb, (size_t)(c0+ci)*H*W + (size_t)gy*W + gx, xf);
      tin[ci][y][x] = v;
    }
    for (int i=t; i<8*16*9; i+=256){
      int ci = i / 144, r = i % 144, co = r/9, k = r%9;
      wl[ci][co][k] = b2f(Wm[(((size_t)gb*Cout + coB+co)*Cin + c0+ci)*9 + k]);
    }
    __syncthreads();
    #pragma unroll 1
    for (int ci=0; ci<8; ci++){
      float in[4][4];
      #pragma unroll
      for (int r=0; r<4; r++){
        const float* row = &tin[ci][oy+r][ox];
        in[r][0]=row[0]; in[r][1]=row[1]; in[r][2]=row[2]; in[r][3]=row[3];
      }
      #pragma unroll
      for (int co=0; co<16; co++){
        const float4* wv = reinterpret_cast<const float4*>(&wl[ci][co][0]);
        float4 wa = wv[0], wb = wv[1];
        float w8 = wl[ci][co][8];
        #pragma unroll
        for (int r2=0; r2<2; r2++)
          #pragma unroll
          for (int c2=0; c2<2; c2++){
            acc[co][r2][c2] += wa.x*in[r2  ][c2] + wa.y*in[r2  ][c2+1] + wa.z*in[r2  ][c2+2]
                             + wa.w*in[r2+1][c2] + wb.x*in[r2+1][c2+1] + wb.y*in[r2+1][c2+2]
                             + wb.z*in[r2+2][c2] + wb.w*in[r2+2][c2+1] + w8  *in[r2+2][c2+2];
          }
      }
    }
    __syncthreads();
  }
  float nwv[16];
  #pragma unroll
  for (int co=0; co<16; co++) nwv[co] = ldf(nw, coB+co, isf32);
  #pragma unroll
  for (int r2=0; r2<2; r2++)
    #pragma unroll
    for (int c2=0; c2<2; c2++){
      int gy = ty0 + oy + r2, gx = tx0 + ox + c2;
      float n = ldf(noise, ((size_t)gb*H + gy)*W + gx, isf32);
      #pragma unroll
      for (int co=0; co<16; co++){
        float v = acc[co][r2][c2] + nwv[co] * n;
        v = (v >= 0.f) ? v : 0.2f*v;
        Yb[((size_t)(coB+co)*H + gy)*W + gx] = f2b(v);
      }
    }
}

// ---------------- 3x3 conv, stride 2, pad 1, fused noise+lrelu ----------------
__global__ __launch_bounds__(256) void conv3x3_s2(const bf16* __restrict__ X,
    long long xbs, int Cin, int Hin,
    const bf16* __restrict__ Wm, const void* __restrict__ noise,
    const void* __restrict__ nw, bf16* __restrict__ Y, long long ybs,
    int Cout, int b0, const int* __restrict__ dflag){
  int isf32 = *dflag;
  const int Win = Hin;
  const int Ho = Hin >> 1, Wo = Ho;
  const int tilesX = Ho >> 4;
  int tile = blockIdx.x;
  int tx0 = (tile % tilesX) * 16;   // output coords
  int ty0 = (tile / tilesX) * 16;
  int coB = blockIdx.y * 16;
  int zz  = blockIdx.z;
  int gb  = b0 + zz;
  __shared__ float tin[8][33][34];
  __shared__ float wl[8][16][12];
  int t = threadIdx.x;
  const bf16* Xb = X + (size_t)zz * xbs;
  bf16*       Yb = Y + (size_t)zz * ybs;
  float acc[16];
  #pragma unroll
  for (int co=0; co<16; co++) acc[co] = 0.f;
  int oy = t >> 4, ox = t & 15;
  int nchunks = Cin >> 3;
  #pragma unroll 1
  for (int ch=0; ch<nchunks; ch++){
    int c0 = ch*8;
    for (int i=t; i<8*33*33; i+=256){
      int ci = i / 1089, rem = i % 1089, y = rem / 33, x = rem % 33;
      int gy = 2*ty0 - 1 + y, gx = 2*tx0 - 1 + x;
      float v = 0.f;
      if (gy>=0 && gy<Hin && gx>=0 && gx<Win)
        v = b2f(Xb[(size_t)(c0+ci)*Hin*Win + (size_t)gy*Win + gx]);
      tin[ci][y][x] = v;
    }
    for (int i=t; i<8*16*9; i+=256){
      int ci = i / 144, r = i % 144, co = r/9, k = r%9;
      wl[ci][co][k] = b2f(Wm[(((size_t)gb*Cout + coB+co)*Cin + c0+ci)*9 + k]);
    }
    __syncthreads();
    #pragma unroll 1
    for (int ci=0; ci<8; ci++){
      float in9[3][3];
      #pragma unroll
      for (int r=0; r<3; r++){
        const float* row = &tin[ci][2*oy + r][2*ox];
        in9[r][0]=row[0]; in9[r][1]=row[1]; in9[r][2]=row[2];
      }
      #pragma unroll
      for (int co=0; co<16; co++){
        const float4* wv = reinterpret_cast<const float4*>(&wl[ci][co][0]);
        float4 wa = wv[0], wb = wv[1];
        float w8 = wl[ci][co][8];
        acc[co] += wa.x*in9[0][0] + wa.y*in9[0][1] + wa.z*in9[0][2]
                 + wa.w*in9[1][0] + wb.x*in9[1][1] + wb.y*in9[1][2]
                 + wb.z*in9[2][0] + wb.w*in9[2][1] + w8  *in9[2][2];
      }
    }
    __syncthreads();
  }
  int gy = ty0 + oy, gx = tx0 + ox;
  float n = ldf(noise, ((size_t)gb*Ho + gy)*Wo + gx, isf32);
  #pragma unroll
  for (int co=0; co<16; co++){
    float v = acc[co] + ldf(nw, coB+co, isf32) * n;
    v = (v >= 0.f) ? v : 0.2f*v;
    Yb[((size_t)(coB+co)*Ho + gy)*Wo + gx] = f2b(v);
  }
}

// ---------------- bilinear resize (32x32 -> 256x240) + 1x1 to-gray ----------------
// grid: (240, nb). b = b0 + blockIdx.y; X offset blockIdx.y*xbs elements.
__global__ __launch_bounds__(256) void resize_rgb(const bf16* __restrict__ X,
    long long xbs, const bf16* __restrict__ wr, void* __restrict__ out, int b0,
    const int* __restrict__ dflag){
  int isf32 = *dflag;
  int b = b0 + blockIdx.y;
  const bf16* Xb = X + (size_t)blockIdx.y * xbs;
  int i = blockIdx.x*256 + threadIdx.x;           // 61440 per batch
  int x = i % 240;
  int y = i / 240;
  float sy = (y + 0.5f)*0.125f - 0.5f;
  float sx = (x + 0.5f)*(32.0f/240.0f) - 0.5f;
  float y0f = floorf(sy), x0f = floorf(sx);
  float fy = sy - y0f, fx = sx - x0f;
  int y0 = (int)y0f, x0 = (int)x0f;
  int y1 = min(y0+1, 31), x1 = min(x0+1, 31);
  y0 = max(y0, 0); x0 = max(x0, 0);
  float acc = 0.f;
  for (int ci=0; ci<32; ci++){
    const bf16* p = Xb + (size_t)ci*1024;
    float v00 = b2f(p[y0*32 + x0]), v01 = b2f(p[y0*32 + x1]);
    float v10 = b2f(p[y1*32 + x0]), v11 = b2f(p[y1*32 + x1]);
    float v = (1.f-fy)*((1.f-fx)*v00 + fx*v01) + fy*((1.f-fx)*v10 + fx*v11);
    acc += b2f(wr[b*32 + ci]) * v;
  }
  stf(out, (size_t)b*61440 + i, isf32, acc);
}

extern "C" void kernel_launch(void* const* d_in, const int* in_sizes, int n_in,
                              void* d_out, int out_size, void* d_ws, size_t ws_size,
                              hipStream_t stream){
  const void* z        = d_in[0];
  const int*  labels   = (const int*)d_in[1];
  const void* emb      = d_in[2];
  const void* map_W    = d_in[3];
  const void* map_b    = d_in[4];
  const void* map_g    = d_in[5];
  const void* map_beta = d_in[6];
  const void* cst      = d_in[7];
  const void* cw0 = d_in[8];   const void* cm0 = d_in[9];
  const void* cw1 = d_in[10];  const void* cm1 = d_in[11];
  const void* n1w = d_in[12];  const void* n2w = d_in[13];
  const void* cw2 = d_in[14];  const void* cm2 = d_in[15];
  const void* cw3 = d_in[16];  const void* cm3 = d_in[17];
  const void* n3w = d_in[18];  const void* n4w = d_in[19];
  const void* cw4 = d_in[20];  const void* cm4 = d_in[21];
  const void* cw5 = d_in[22];  const void* cm5 = d_in[23];
  const void* n5w = d_in[24];  const void* n6w = d_in[25];
  const void* cw6 = d_in[26];  const void* cm6 = d_in[27];
  const void* n1a = d_in[28];  const void* n1b = d_in[29];
  const void* n2a = d_in[30];  const void* n2b = d_in[31];
  const void* n3a = d_in[32];  const void* n3b = d_in[33];

  int*   flag  = (int*)d_ws;
  float* xA    = (float*)((char*)d_ws + 256);
  float* xB    = (float*)((char*)d_ws + 16640);
  float* s_all = (float*)((char*)d_ws + 33024);
  bf16*  wmod  = (bf16*)((char*)d_ws + 51456);
  char*  arenas = (char*)d_ws + 6983680;

  detect_dtype<<<1,256,0,stream>>>((const unsigned short*)cst, flag);
  map_init<<<16,256,0,stream>>>(z, labels, emb, xA, flag);
  float* cur = xA; float* nxt = xB;
  for (int l=0; l<8; l++){
    map_layer<<<512,64,0,stream>>>(cur, nxt, map_W, (size_t)l*512*512,
                                   map_b, map_g, map_beta, (size_t)l*512, flag);
    float* tmp = cur; cur = nxt; nxt = tmp;
  }
  styles_kernel<<<4608,64,0,stream>>>(cur, s_all, cm0, cm1, cm2, cm3, cm4, cm5, cm6, flag);
  modw_kernel<<<3592,64,0,stream>>>(s_all, wmod, cw0, cw1, cw2, cw3, cw4, cw5, cw6, flag);

  bf16* wm0 = wmod;
  bf16* wm1 = wmod + 1179648;
  bf16* wm2 = wmod + 2359296;
  bf16* wm3 = wmod + 2949120;
  bf16* wm4 = wmod + 3244032;
  bf16* wm5 = wmod + 3391488;
  bf16* wm6 = wmod + 3465216;

  const long long A1  = 128LL*256*256;  // 8,388,608
  const long long A1B = 128LL*128*128;  // 2,097,152
  const long long A2  = 64LL*128*128;   // 1,048,576
  const long long A2B = 64LL*64*64;     //   262,144
  const long long A3  = 32LL*64*64;     //   131,072
  const long long A3B = 32LL*32*32;     //    32,768

  const size_t needA = 6983680ULL + 134217728ULL + 33554432ULL;              // 174,755,840
  const size_t needB = 6983680ULL + 16777216ULL + 33554432ULL + 4194304ULL;  //  61,509,632

  if (ws_size >= needA){
    // -------- Path A: full batch (z=8) everywhere --------
    bf16* pA = (bf16*)arenas;                       // 134 MB
    bf16* pB = (bf16*)(arenas + 134217728LL);       // 33.5 MB
    conv3x3_s1<<<dim3(64,8,8),256,0,stream>>>(cst, 1, 0,   128, 256, wm0, n1a, n1w, pA, A1,  128, 0, flag);
    conv3x3_s2<<<dim3(64,8,8),256,0,stream>>>(pA,      A1, 128, 256, wm1, n1b, n2w, pB, A1B, 128, 0, flag);
    conv3x3_s1<<<dim3(16,4,8),256,0,stream>>>(pB, 0, A1B, 128, 128, wm2, n2a, n3w, pA, A2,  64, 0, flag);
    conv3x3_s2<<<dim3(16,4,8),256,0,stream>>>(pA,     A2,  64, 128, wm3, n2b, n4w, pB, A2B, 64, 0, flag);
    conv3x3_s1<<<dim3(4,2,8),256,0,stream>>>(pB, 0, A2B, 64, 64, wm4, n3a, n5w, pA, A3,  32, 0, flag);
    conv3x3_s2<<<dim3(4,2,8),256,0,stream>>>(pA,     A3,  32, 64, wm5, n3b, n6w, pB, A3B, 32, 0, flag);
    resize_rgb<<<dim3(240,8),256,0,stream>>>(pB, A3B, wm6, d_out, 0, flag);
  } else if (ws_size >= needB){
    // -------- Path B: b1 per-batch into full a1b; z=8 for b2/b3/resize --------
    bf16* pA = (bf16*)arenas;                       // 16.8 MB: a1 scratch, later a2/a3... (a3 goes to B)
    bf16* pB = (bf16*)(arenas + 16777216LL);        // 33.5 MB: a1b full, later a3 full
    bf16* pC = (bf16*)(arenas + 16777216LL + 33554432LL); // 4.2 MB: a2b full, later a3b full
    for (int b=0; b<8; b++){
      conv3x3_s1<<<dim3(64,8,1),256,0,stream>>>(cst, 1, 0, 128, 256, wm0, n1a, n1w, pA, 0, 128, b, flag);
      conv3x3_s2<<<dim3(64,8,1),256,0,stream>>>(pA, 0, 128, 256, wm1, n1b, n2w, pB + (size_t)b*A1B, 0, 128, b, flag);
    }
    conv3x3_s1<<<dim3(16,4,8),256,0,stream>>>(pB, 0, A1B, 128, 128, wm2, n2a, n3w, pA, A2,  64, 0, flag);
    conv3x3_s2<<<dim3(16,4,8),256,0,stream>>>(pA,     A2,  64, 128, wm3, n2b, n4w, pC, A2B, 64, 0, flag);
    conv3x3_s1<<<dim3(4,2,8),256,0,stream>>>(pC, 0, A2B, 64, 64, wm4, n3a, n5w, pB, A3,  32, 0, flag);
    conv3x3_s2<<<dim3(4,2,8),256,0,stream>>>(pB,     A3,  32, 64, wm5, n3b, n6w, pC, A3B, 32, 0, flag);
    resize_rgb<<<dim3(240,8),256,0,stream>>>(pC, A3B, wm6, d_out, 0, flag);
  } else {
    // -------- Path C: round-3 known-good per-batch ping-pong --------
    bf16* P = (bf16*)arenas;                        // 16.8 MB
    bf16* Q = (bf16*)(arenas + 16777216LL);         //  4.2 MB
    for (int b=0; b<8; b++){
      conv3x3_s1<<<dim3(64,8,1),256,0,stream>>>(cst, 1, 0, 128, 256, wm0, n1a, n1w, P, 0, 128, b, flag);
      conv3x3_s2<<<dim3(64,8,1),256,0,stream>>>(P, 0, 128, 256, wm1, n1b, n2w, Q, 0, 128, b, flag);
      conv3x3_s1<<<dim3(16,4,1),256,0,stream>>>(Q, 0, 0, 128, 128, wm2, n2a, n3w, P, 0, 64, b, flag);
      conv3x3_s2<<<dim3(16,4,1),256,0,stream>>>(P, 0, 64, 128, wm3, n2b, n4w, Q, 0, 64, b, flag);
      conv3x3_s1<<<dim3(4,2,1),256,0,stream>>>(Q, 0, 0, 64, 64, wm4, n3a, n5w, P, 0, 32, b, flag);
      conv3x3_s2<<<dim3(4,2,1),256,0,stream>>>(P, 0, 32, 64, wm5, n3b, n6w, Q, 0, 32, b, flag);
      resize_rgb<<<dim3(240,1),256,0,stream>>>(Q, 0, wm6, d_out, b, flag);
    }
  }
}

// Round 5
// 698.633 us; speedup vs baseline: 17.9304x; 8.6499x over previous
//
#include <hip/hip_runtime.h>
#include <hip/hip_bf16.h>

// StyleGAN2 generator forward, MI355X round-5: MFMA implicit-GEMM convs.
// - Internal activations NHWC bf16 (ci innermost) so LDS staging is a straight
//   vector copy and B-fragments are 16B-contiguous ds_read_b128.
// - Modulated weights pre-swizzled (modw_kernel) into exact MFMA A-fragment
//   lane order: WA[b][tap][ci/32][co/16][lane*8+j] -> wave reads lane*16B coalesced.
// - mfma_f32_16x16x32_bf16; C/D: col=lane&15 (pixel), row=quad*4+reg (co).
// - ws_size >= 174,755,840 proven by round 4 (Path A ran); layout fits exactly:
//   cstT borrows the a1b arena (disjoint lifetimes).
//
// Workspace layout (bytes):
//   0          flag
//   256        xA   4096 f32
//   16640      xB   4096 f32
//   33024      s_all 4608 f32
//   51456      wmodA 3,465,472 bf16 (6,930,944 B)
//   6,983,680  A1 arena 134,217,728  (a1 / a2 / a3)
//   141,201,408 A2 arena 33,554,432  (cstT during conv1 / a1b / a2b / a3b)
//   total 174,755,840

typedef __hip_bfloat16 bf16;
typedef __attribute__((ext_vector_type(8))) short bf16x8;
typedef __attribute__((ext_vector_type(4))) float f32x4;

__device__ __forceinline__ float b2f(bf16 v){ return __bfloat162float(v); }
__device__ __forceinline__ bf16  f2b(float v){ return __float2bfloat16(v); }
__device__ __forceinline__ unsigned short bbits(float v){
  bf16 h = f2b(v); union { bf16 h; unsigned short u; } x; x.h = h; return x.u;
}
__device__ __forceinline__ float ldf(const void* p, size_t i, int isf32){
  return isf32 ? ((const float*)p)[i] : b2f(((const bf16*)p)[i]);
}
__device__ __forceinline__ void stf(void* p, size_t i, int isf32, float v){
  if (isf32) ((float*)p)[i] = v; else ((bf16*)p)[i] = f2b(v);
}

// ---------------- dtype detector ----------------
__global__ __launch_bounds__(256) void detect_dtype(const unsigned short* __restrict__ cst,
    int* __restrict__ flag){
  __shared__ int cnt[256];
  int t = threadIdx.x, c = 0;
  for (int i=t; i<4096; i+=256){
    unsigned short w = cst[i];
    int mag = w & 0x7FFF;
    int e = mag >> 7;
    if (mag == 0 || (e >= 96 && e <= 150)) c++;
  }
  cnt[t] = c; __syncthreads();
  for (int s=128; s>0; s>>=1){ if (t<s) cnt[t] += cnt[t+s]; __syncthreads(); }
  if (t == 0) *flag = (cnt[0] >= 3500) ? 0 : 1;
}

// ---------------- const CHW -> NHWC bf16 ----------------
__global__ __launch_bounds__(256) void cvt_const(const void* __restrict__ cst,
    short* __restrict__ out, const int* __restrict__ dflag){
  int isf32 = *dflag;
  __shared__ __align__(16) short sh[64*136];
  int t = threadIdx.x;
  int p0 = blockIdx.x * 64;                         // 1024 blocks x 64 pixels
  for (int i=t; i<128*64; i+=256){
    int ci = i >> 6, px = i & 63;
    float v = ldf(cst, (size_t)ci*65536 + p0 + px, isf32);
    sh[px*136 + ci] = (short)bbits(v);
  }
  __syncthreads();
  for (int i=t; i<64*16; i+=256){
    int px = i >> 4, c8 = (i & 15) * 8;
    bf16x8 val = *(const bf16x8*)&sh[px*136 + c8];
    *(bf16x8*)(out + ((size_t)(p0+px))*128 + c8) = val;
  }
}

// ---------------- mapping network ----------------
__global__ __launch_bounds__(256) void map_init(const void* __restrict__ z,
    const int* __restrict__ labels, const void* __restrict__ emb,
    float* __restrict__ x0, const int* __restrict__ dflag){
  int isf32 = *dflag;
  int i = blockIdx.x*256 + threadIdx.x;
  int b = i >> 9, k = i & 511;
  x0[i] = ldf(z, i, isf32) + ldf(emb, (size_t)labels[b]*512 + k, isf32);
}

__global__ __launch_bounds__(64) void map_layer(const float* __restrict__ xin,
    float* __restrict__ xout, const void* __restrict__ W, size_t wOff,
    const void* __restrict__ bl, const void* __restrict__ gl,
    const void* __restrict__ betal, size_t vOff, const int* __restrict__ dflag){
  int isf32 = *dflag;
  int j = blockIdx.x;
  int l = threadIdx.x;
  int b = l >> 3, sp = l & 7;
  float part = 0.f;
  int k0 = sp*64;
  size_t wrow = wOff + (size_t)j*512 + k0;
  for (int k=0; k<64; k++)
    part += xin[b*512 + k0 + k] * ldf(W, wrow + k, isf32);
  part += __shfl_xor(part, 1);
  part += __shfl_xor(part, 2);
  part += __shfl_xor(part, 4);
  float y = part + ldf(bl, vOff + j, isf32);
  float ys[8];
  float mu = 0.f;
  #pragma unroll
  for (int bb=0; bb<8; bb++){ ys[bb] = __shfl(y, bb*8); mu += ys[bb]; }
  mu *= 0.125f;
  float var = 0.f;
  #pragma unroll
  for (int bb=0; bb<8; bb++){ float d = ys[bb]-mu; var += d*d; }
  var *= 0.125f;
  float xn = (y-mu)*rsqrtf(var+1e-5f)*ldf(gl, vOff + j, isf32) + ldf(betal, vOff + j, isf32);
  xn = (xn >= 0.f) ? xn : 0.2f*xn;
  if (sp == 0) xout[b*512 + j] = xn;
}

// ---------------- styles ----------------
__global__ __launch_bounds__(64) void styles_kernel(const float* __restrict__ w,
    float* __restrict__ s_all,
    const void* m0, const void* m1, const void* m2, const void* m3,
    const void* m4, const void* m5, const void* m6, const int* __restrict__ dflag){
  int isf32 = *dflag;
  int id = blockIdx.x;                            // 4608
  const int offs[8] = {0,1024,2048,3072,3584,4096,4352,4608};
  const int cins[7] = {128,128,128,64,64,32,32};
  const void* ms[7] = {m0,m1,m2,m3,m4,m5,m6};
  int c = 0;
  while (id >= offs[c+1]) c++;
  int r = id - offs[c];
  int Cin = cins[c];
  int b = r / Cin, ci = r % Cin;
  int l = threadIdx.x;
  float acc = 0.f;
  for (int k=l; k<512; k+=64) acc += w[b*512 + k] * ldf(ms[c], (size_t)ci*512 + k, isf32);
  #pragma unroll
  for (int m=1; m<64; m<<=1) acc += __shfl_xor(acc, m);
  if (l == 0) s_all[id] = acc;
}

// ---------------- modulate + demodulate + swizzle to MFMA A-fragment order ----
// Swizzled layout per conv: WA[b][tap][ci/32][co/16][512], element (lane*8+j)
// with lane = ((ci>>3)&3)*16 + (co&15), j = ci&7  (A[m=lane&15][k=quad*8+j]).
// rgb conv (1x1, no demod): plain [b][32].
__global__ __launch_bounds__(64) void modw_kernel(const float* __restrict__ s_all,
    bf16* __restrict__ wmod,
    const void* w0, const void* w1, const void* w2, const void* w3,
    const void* w4, const void* w5, const void* w6, const int* __restrict__ dflag){
  int isf32 = *dflag;
  int bid = blockIdx.x;
  int base, Cout, Cin, soff, wmoff, demod = 1;
  const void* wp;
  if      (bid < 1024){ base=0;    Cout=128; Cin=128; soff=0;    wmoff=0;       wp=w0; }
  else if (bid < 2048){ base=1024; Cout=128; Cin=128; soff=1024; wmoff=1179648; wp=w1; }
  else if (bid < 2560){ base=2048; Cout=64;  Cin=128; soff=2048; wmoff=2359296; wp=w2; }
  else if (bid < 3072){ base=2560; Cout=64;  Cin=64;  soff=3072; wmoff=2949120; wp=w3; }
  else if (bid < 3328){ base=3072; Cout=32;  Cin=64;  soff=3584; wmoff=3244032; wp=w4; }
  else if (bid < 3584){ base=3328; Cout=32;  Cin=32;  soff=4096; wmoff=3391488; wp=w5; }
  else                { base=3584; Cout=1;   Cin=32;  soff=4352; wmoff=3465216; wp=w6; demod=0; }
  int kk = demod ? 9 : 1;
  int L  = Cin * kk;
  int bc = bid - base;
  int b  = bc / Cout, co = bc % Cout;
  float scale = 1.0f / sqrtf((float)L);
  int l = threadIdx.x;
  float part = 0.f;
  for (int e=l; e<L; e+=64){
    int ci = e / kk;
    float v = scale * ldf(wp, (size_t)co*L + e, isf32) * s_all[soff + b*Cin + ci];
    part += v*v;
  }
  #pragma unroll
  for (int m=1; m<64; m<<=1) part += __shfl_xor(part, m);
  float d = demod ? rsqrtf(part + 1e-8f) : 1.0f;
  for (int e=l; e<L; e+=64){
    int ci = e / kk, tap = e % kk;
    float v = scale * ldf(wp, (size_t)co*L + e, isf32) * s_all[soff + b*Cin + ci];
    size_t idx;
    if (demod){
      int c32 = ci >> 5;
      int lane2 = ((ci >> 3) & 3) * 16 + (co & 15);
      int j = ci & 7;
      int mtg = co >> 4;
      idx = (size_t)wmoff +
            ((((size_t)b*9 + tap)*(Cin>>5) + c32)*(Cout>>4) + mtg)*512 + lane2*8 + j;
    } else {
      idx = (size_t)wmoff + (size_t)b*Cin + e;
    }
    wmod[idx] = f2b(v * d);
  }
}

// ---------------- MFMA implicit-GEMM 3x3 conv + noise + lrelu ----------------
// Block 256 thr = 4 waves (2 M-halves x 2 N-halves). Block tile:
//   M = 2*MT*16 = Cout, N = 2*NT*16 pixels (nrowsOut rows x wtile cols).
// K loop: ci chunks of 32; per chunk stage act tile (NHWC) to LDS, then
// 9 taps x MT x NT MFMAs. A-frags from pre-swizzled global (L2-resident).
template<int MT, int NT, int S>
__global__ __launch_bounds__(256) void convmf(
    const short* __restrict__ X, long long xbs, int Cin, int Hin, int Win,
    const bf16* __restrict__ WA, const void* __restrict__ noise,
    const void* __restrict__ nwp, short* __restrict__ Y, long long ybs,
    int Cout, int Hout, int Wout, int wtile, int nrowsOut,
    const int* __restrict__ dflag){
  int isf32 = *dflag;
  const int W_in_t = (S==1) ? (wtile+2) : (2*wtile+1);
  const int R_in   = (S==1) ? (nrowsOut+2) : (2*nrowsOut+1);
  __shared__ __align__(16) short act[15600];      // max 3*130*40
  int t = threadIdx.x;
  int lane = t & 63, wv = t >> 6;
  int mw = wv & 1, nwv = wv >> 1;
  int lanelow = lane & 15, quad = lane >> 4;
  int tiles_x = Wout / wtile;
  int tx = blockIdx.x % tiles_x, ty = blockIdx.x / tiles_x;
  int ox0 = tx * wtile, oy0 = ty * nrowsOut;
  int iy0 = S*oy0 - 1, ix0 = S*ox0 - 1;
  int z = blockIdx.z;
  const short* Xb = X + (size_t)z * xbs;
  short* Yb = Y + (size_t)z * ybs;
  const int Cin32 = Cin >> 5, Cout16 = Cout >> 4;
  const bf16x8* WAimg = (const bf16x8*)WA + (size_t)z * 9 * Cin32 * Cout16 * 64;
  f32x4 acc[MT][NT];
  #pragma unroll
  for (int mt=0; mt<MT; mt++)
    #pragma unroll
    for (int nt=0; nt<NT; nt++) acc[mt][nt] = (f32x4){0.f,0.f,0.f,0.f};
  int rowb[NT], xb[NT];
  #pragma unroll
  for (int nt=0; nt<NT; nt++){
    int nl = nwv*NT*16 + nt*16;
    rowb[nt] = nl / wtile;
    xb[nt]  = nl % wtile + lanelow;
  }
  for (int c32=0; c32<Cin32; c32++){
    int c0 = c32 << 5;
    __syncthreads();                               // WAR: prior reads done
    for (int i=t; i<R_in*W_in_t; i+=256){
      int r = i / W_in_t, x = i % W_in_t;
      int gy = iy0 + r, gx = ix0 + x;
      bf16x8* dst = (bf16x8*)&act[i*40];
      if (gy>=0 && gy<Hin && gx>=0 && gx<Win){
        const bf16x8* src = (const bf16x8*)(Xb + ((size_t)gy*Win + gx)*Cin + c0);
        dst[0]=src[0]; dst[1]=src[1]; dst[2]=src[2]; dst[3]=src[3];
      } else {
        bf16x8 zz = (bf16x8){0,0,0,0,0,0,0,0};
        dst[0]=zz; dst[1]=zz; dst[2]=zz; dst[3]=zz;
      }
    }
    __syncthreads();
    #pragma unroll
    for (int tap=0; tap<9; tap++){
      int ky = tap/3, kx = tap%3;
      bf16x8 afr[MT], bfr[NT];
      #pragma unroll
      for (int mt=0; mt<MT; mt++){
        int mtg = mw*MT + mt;
        afr[mt] = WAimg[(((size_t)tap*Cin32 + c32)*Cout16 + mtg)*64 + lane];
      }
      #pragma unroll
      for (int nt=0; nt<NT; nt++){
        int off = ((S*rowb[nt] + ky)*W_in_t + (S*xb[nt] + kx))*40 + quad*8;
        bfr[nt] = *(const bf16x8*)&act[off];
      }
      #pragma unroll
      for (int mt=0; mt<MT; mt++)
        #pragma unroll
        for (int nt=0; nt<NT; nt++)
          acc[mt][nt] = __builtin_amdgcn_mfma_f32_16x16x32_bf16(
              afr[mt], bfr[nt], acc[mt][nt], 0, 0, 0);
    }
  }
  // epilogue: D col=lane&15 -> pixel (same lanelow as B), row=quad*4+i -> co.
  #pragma unroll
  for (int nt=0; nt<NT; nt++){
    int oy = oy0 + rowb[nt], ox = ox0 + xb[nt];
    float nv = ldf(noise, ((size_t)z*Hout + oy)*Wout + ox, isf32);
    #pragma unroll
    for (int mt=0; mt<MT; mt++){
      int co0 = (mw*MT + mt)*16 + quad*4;
      ushort4 pk;
      float v0 = acc[mt][nt][0] + ldf(nwp, co0+0, isf32)*nv; v0 = (v0>=0.f)?v0:0.2f*v0;
      float v1 = acc[mt][nt][1] + ldf(nwp, co0+1, isf32)*nv; v1 = (v1>=0.f)?v1:0.2f*v1;
      float v2 = acc[mt][nt][2] + ldf(nwp, co0+2, isf32)*nv; v2 = (v2>=0.f)?v2:0.2f*v2;
      float v3 = acc[mt][nt][3] + ldf(nwp, co0+3, isf32)*nv; v3 = (v3>=0.f)?v3:0.2f*v3;
      pk.x = bbits(v0); pk.y = bbits(v1); pk.z = bbits(v2); pk.w = bbits(v3);
      *(ushort4*)&Yb[((size_t)oy*Wout + ox)*Cout + co0] = pk;
    }
  }
}

// ---------------- bilinear resize (NHWC 32x32x32 -> 256x240) + 1x1 to-gray ----
__global__ __launch_bounds__(256) void resize_rgb(const short* __restrict__ X,
    long long xbs, const bf16* __restrict__ wr, void* __restrict__ out,
    const int* __restrict__ dflag){
  int isf32 = *dflag;
  int b = blockIdx.y;
  const short* Xb = X + (size_t)b * xbs;
  int i = blockIdx.x*256 + threadIdx.x;           // 61440 per batch
  int x = i % 240;
  int y = i / 240;
  float sy = (y + 0.5f)*0.125f - 0.5f;
  float sx = (x + 0.5f)*(32.0f/240.0f) - 0.5f;
  float y0f = floorf(sy), x0f = floorf(sx);
  float fy = sy - y0f, fx = sx - x0f;
  int y0 = (int)y0f, x0 = (int)x0f;
  int y1 = min(y0+1, 31), x1 = min(x0+1, 31);
  y0 = max(y0, 0); x0 = max(x0, 0);
  const short* p00 = Xb + ((size_t)(y0*32 + x0))*32;
  const short* p01 = Xb + ((size_t)(y0*32 + x1))*32;
  const short* p10 = Xb + ((size_t)(y1*32 + x0))*32;
  const short* p11 = Xb + ((size_t)(y1*32 + x1))*32;
  float w00 = (1.f-fy)*(1.f-fx), w01 = (1.f-fy)*fx, w10 = fy*(1.f-fx), w11 = fy*fx;
  float acc = 0.f;
  for (int ci=0; ci<32; ci++){
    float v = w00*b2f(((const bf16*)p00)[ci]) + w01*b2f(((const bf16*)p01)[ci])
            + w10*b2f(((const bf16*)p10)[ci]) + w11*b2f(((const bf16*)p11)[ci]);
    acc += b2f(wr[b*32 + ci]) * v;
  }
  stf(out, (size_t)b*61440 + i, isf32, acc);
}

extern "C" void kernel_launch(void* const* d_in, const int* in_sizes, int n_in,
                              void* d_out, int out_size, void* d_ws, size_t ws_size,
                              hipStream_t stream){
  const void* z        = d_in[0];
  const int*  labels   = (const int*)d_in[1];
  const void* emb      = d_in[2];
  const void* map_W    = d_in[3];
  const void* map_b    = d_in[4];
  const void* map_g    = d_in[5];
  const void* map_beta = d_in[6];
  const void* cst      = d_in[7];
  const void* cw0 = d_in[8];   const void* cm0 = d_in[9];
  const void* cw1 = d_in[10];  const void* cm1 = d_in[11];
  const void* n1w = d_in[12];  const void* n2w = d_in[13];
  const void* cw2 = d_in[14];  const void* cm2 = d_in[15];
  const void* cw3 = d_in[16];  const void* cm3 = d_in[17];
  const void* n3w = d_in[18];  const void* n4w = d_in[19];
  const void* cw4 = d_in[20];  const void* cm4 = d_in[21];
  const void* cw5 = d_in[22];  const void* cm5 = d_in[23];
  const void* n5w = d_in[24];  const void* n6w = d_in[25];
  const void* cw6 = d_in[26];  const void* cm6 = d_in[27];
  const void* n1a = d_in[28];  const void* n1b = d_in[29];
  const void* n2a = d_in[30];  const void* n2b = d_in[31];
  const void* n3a = d_in[32];  const void* n3b = d_in[33];

  int*   flag  = (int*)d_ws;
  float* xA    = (float*)((char*)d_ws + 256);
  float* xB    = (float*)((char*)d_ws + 16640);
  float* s_all = (float*)((char*)d_ws + 33024);
  bf16*  wmod  = (bf16*)((char*)d_ws + 51456);
  short* A1    = (short*)((char*)d_ws + 6983680);    // 134,217,728 B
  short* A2    = (short*)((char*)d_ws + 141201408);  //  33,554,432 B

  detect_dtype<<<1,256,0,stream>>>((const unsigned short*)cst, flag);
  cvt_const<<<1024,256,0,stream>>>(cst, A2, flag);   // cstT in A2 (dead after conv1)
  map_init<<<16,256,0,stream>>>(z, labels, emb, xA, flag);
  float* cur = xA; float* nxt = xB;
  for (int l=0; l<8; l++){
    map_layer<<<512,64,0,stream>>>(cur, nxt, map_W, (size_t)l*512*512,
                                   map_b, map_g, map_beta, (size_t)l*512, flag);
    float* tmp = cur; cur = nxt; nxt = tmp;
  }
  styles_kernel<<<4608,64,0,stream>>>(cur, s_all, cm0, cm1, cm2, cm3, cm4, cm5, cm6, flag);
  modw_kernel<<<3592,64,0,stream>>>(s_all, wmod, cw0, cw1, cw2, cw3, cw4, cw5, cw6, flag);

  bf16* wm0 = wmod;
  bf16* wm1 = wmod + 1179648;
  bf16* wm2 = wmod + 2359296;
  bf16* wm3 = wmod + 2949120;
  bf16* wm4 = wmod + 3244032;
  bf16* wm5 = wmod + 3391488;
  bf16* wm6 = wmod + 3465216;

  const long long A1e  = 256LL*256*128;  // a1  NHWC elems/img
  const long long A1Be = 128LL*128*128;  // a1b
  const long long A2e  = 128LL*128*64;   // a2
  const long long A2Be = 64LL*64*64;     // a2b
  const long long A3e  = 64LL*64*32;     // a3
  const long long A3Be = 32LL*32*32;     // a3b

  // conv1: cstT(A2) -> a1(A1).  M=128(MT4), N=128px(NT4), s1, wtile=128
  convmf<4,4,1><<<dim3(512,1,8),256,0,stream>>>(A2, 0, 128, 256, 256,
      wm0, n1a, n1w, A1, A1e, 128, 256, 256, 128, 1, flag);
  // conv2: a1(A1) -> a1b(A2).  M=128(MT4), N=64px(NT2), s2, wtile=64
  convmf<4,2,2><<<dim3(256,1,8),256,0,stream>>>(A1, A1e, 128, 256, 256,
      wm1, n1b, n2w, A2, A1Be, 128, 128, 128, 64, 1, flag);
  // conv3: a1b(A2) -> a2(A1).  M=64(MT2), N=128px(NT4), s1, wtile=128
  convmf<2,4,1><<<dim3(128,1,8),256,0,stream>>>(A2, A1Be, 128, 128, 128,
      wm2, n2a, n3w, A1, A2e, 64, 128, 128, 128, 1, flag);
  // conv4: a2(A1) -> a2b(A2).  M=64(MT2), N=64px(NT2), s2, wtile=64
  convmf<2,2,2><<<dim3(64,1,8),256,0,stream>>>(A1, A2e, 64, 128, 128,
      wm3, n2b, n4w, A2, A2Be, 64, 64, 64, 64, 1, flag);
  // conv5: a2b(A2) -> a3(A1).  M=32(MT1), N=128px(NT4: 2 rows x 64), s1
  convmf<1,4,1><<<dim3(32,1,8),256,0,stream>>>(A2, A2Be, 64, 64, 64,
      wm4, n3a, n5w, A1, A3e, 32, 64, 64, 64, 2, flag);
  // conv6: a3(A1) -> a3b(A2).  M=32(MT1), N=64px(NT2: 2 rows x 32), s2
  convmf<1,2,2><<<dim3(16,1,8),256,0,stream>>>(A1, A3e, 32, 64, 64,
      wm5, n3b, n6w, A2, A3Be, 32, 32, 32, 32, 2, flag);
  // resize + to-gray -> d_out
  resize_rgb<<<dim3(240,8),256,0,stream>>>(A2, A3Be, wm6, d_out, flag);
}